// Round 11
// baseline (1168.157 us; speedup 1.0000x reference)
//
#include <hip/hip_runtime.h>

// GCNEncoder: B=32, N=1024, D=1024, L=2, D_FF=512
// R15 = R14 + (a) transpose fused into the qk GEMM launch (grid-split:
// wgid < ngemm -> gemm blocks, else 64x64 transpose blocks; independent
// data, transpose backfills CUs as gemm blocks drain — kills the serial
// ~25us transpose + a launch gap, x2 layers) + (b) setprio removed from
// the GEMM K-loop (m190: setprio is negative on lockstep GEMM; it was
// never isolated since R5 — unfused gemm_bt dur gives the clean A/B).
// GEMM core (R7/R14): 256x256 tile, 8 waves, phase-ahead preload,
// 2 barriers/K-tile, vmcnt(4)@P3 / stage A@P4, chunked-XCD swizzle,
// xor-swizzled 128KiB LDS. nT even, M%256==0, N%256==0 at all sites.

#define SM_SCALE 0.04419417382415922f  // 1/sqrt(512)

using bf16x8 = __attribute__((ext_vector_type(8))) short;
using f32x4  = __attribute__((ext_vector_type(4))) float;

__device__ __forceinline__ short f2bf(float f) {
  union { float f; unsigned u; } x; x.f = f;
  unsigned r = x.u + 0x7fffu + ((x.u >> 16) & 1u);  // RNE
  return (short)(r >> 16);
}
__device__ __forceinline__ float bf2f(short s) {
  union { unsigned u; float f; } x;
  x.u = ((unsigned)(unsigned short)s) << 16;
  return x.f;
}

typedef const __attribute__((address_space(1))) void* gp1_t;
typedef __attribute__((address_space(3))) void* lp3_t;
__device__ __forceinline__ void ld_lds16(const void* g, void* l) {
  __builtin_amdgcn_global_load_lds((gp1_t)g, (lp3_t)l, 16, 0, 0);
}

// staging: one half-tile = [128][64] shorts; 512 threads x 2 loads x 16B.
// source col-group = (tid&7) ^ (row&7) so phys cg == logical cg ^ (row&7)
// (xor-swizzle, conflict-free ds_read_b128: 2 lanes/bank).
#define STAGE_A(BUF, AH, KO)                                                 \
  { const short* _sp = A + (long)((AH) * 128 + r0) * lda + (KO) + cl;        \
    char* _dp = (char*)As + (((BUF) * 32768) + ((AH) * 16384) + sdst);       \
    ld_lds16(_sp, _dp);                                                      \
    ld_lds16(_sp + 64 * lda, _dp + 8192); }

#define STAGE_B(BUF, BH, KO)                                                 \
  { const short* _sp = Bt + (long)((BH) * 128 + r0) * ldb + (KO) + cl;       \
    char* _dp = (char*)Bs + (((BUF) * 32768) + ((BH) * 16384) + sdst);       \
    ld_lds16(_sp, _dp);                                                      \
    ld_lds16(_sp + 64 * ldb, _dp + 8192); }

#define MFMA16(AF, BF, ACC_R, ACC_C)                                         \
  _Pragma("unroll") for (int j = 0; j < 4; ++j)                              \
    _Pragma("unroll") for (int n = 0; n < 2; ++n) {                          \
      acc[(ACC_R) + j][(ACC_C) + n] = __builtin_amdgcn_mfma_f32_16x16x32_bf16(\
          AF[j][0], BF[n][0], acc[(ACC_R) + j][(ACC_C) + n], 0, 0, 0);       \
      acc[(ACC_R) + j][(ACC_C) + n] = __builtin_amdgcn_mfma_f32_16x16x32_bf16(\
          AF[j][1], BF[n][1], acc[(ACC_R) + j][(ACC_C) + n], 0, 0, 0);       \
    }

#define KTILE(T, BUF)                                                        \
  {                                                                          \
    /* P1: preload b1(T); MFMA a0 x b0 -> acc[0..3][0..1] */                 \
    _Pragma("unroll") for (int j = 0; j < 2; ++j) {                          \
      b1[j][0] = *(const bf16x8*)(Brd + (BUF) * 16384 + (2 + j) * 1024 + sw0);\
      b1[j][1] = *(const bf16x8*)(Brd + (BUF) * 16384 + (2 + j) * 1024 + sw1);\
    }                                                                        \
    MFMA16(a0, b0, 0, 0)                                                     \
    /* P2: preload a1(T); MFMA a0 x b1 -> acc[0..3][2..3] */                 \
    _Pragma("unroll") for (int j = 0; j < 4; ++j) {                          \
      a1[j][0] = *(const bf16x8*)(Ard + (BUF) * 16384 + (4 + j) * 1024 + sw0);\
      a1[j][1] = *(const bf16x8*)(Ard + (BUF) * 16384 + (4 + j) * 1024 + sw1);\
    }                                                                        \
    MFMA16(a0, b1, 0, 2)                                                     \
    /* P3: publish reads; stage B(T+2)->buf(T); gate; preload a0(T+1) */     \
    asm volatile("s_waitcnt lgkmcnt(0)" ::: "memory");                       \
    __builtin_amdgcn_s_barrier();                                            \
    if ((T) + 2 < nT) {                                                      \
      STAGE_B((BUF), 0, ((T) + 2) * 64)                                      \
      STAGE_B((BUF), 1, ((T) + 2) * 64)                                      \
      asm volatile("s_waitcnt vmcnt(4)" ::: "memory");                       \
    } else {                                                                 \
      asm volatile("s_waitcnt vmcnt(0)" ::: "memory");                       \
    }                                                                        \
    __builtin_amdgcn_s_barrier();                                            \
    _Pragma("unroll") for (int j = 0; j < 4; ++j) {                          \
      a0[j][0] = *(const bf16x8*)(Ard + ((BUF) ^ 1) * 16384 + j * 1024 + sw0);\
      a0[j][1] = *(const bf16x8*)(Ard + ((BUF) ^ 1) * 16384 + j * 1024 + sw1);\
    }                                                                        \
    MFMA16(a1, b0, 4, 0)                                                     \
    /* P4: stage A(T+2)->buf(T); preload b0(T+1); MFMA a1 x b1 */            \
    if ((T) + 2 < nT) {                                                      \
      STAGE_A((BUF), 0, ((T) + 2) * 64)                                      \
      STAGE_A((BUF), 1, ((T) + 2) * 64)                                      \
    }                                                                        \
    _Pragma("unroll") for (int j = 0; j < 2; ++j) {                          \
      b0[j][0] = *(const bf16x8*)(Brd + ((BUF) ^ 1) * 16384 + j * 1024 + sw0);\
      b0[j][1] = *(const bf16x8*)(Brd + ((BUF) ^ 1) * 16384 + j * 1024 + sw1);\
    }                                                                        \
    MFMA16(a1, b1, 4, 2)                                                     \
  }

// ---------------- GEMM core: C(bf16) = A (MxK) * Bt^T (Bt NxK).
// v = virtual block id (already XCD-chunk swizzled). 512 threads.
template <int MODE, bool BATCHED>
__device__ __forceinline__ void gemm_core(
    const short* __restrict__ A, const short* __restrict__ Bt,
    short* __restrict__ o16, const float* __restrict__ bias,
    int N, int K, long lda, long ldb, long sA, long sB, long sC,
    int v, short* As, short* Bs)
{
  const int tid  = threadIdx.x;
  const int lane = tid & 63;
  const int wave = tid >> 6;        // 0..7
  const int wm = wave >> 2;         // 0..1 -> 128-row half
  const int wn = wave & 3;          // 0..3 -> 64-col slice
  const int l15 = lane & 15, quad = lane >> 4;
  int bz, bmt, bnt;
  if (BATCHED) { bz = v >> 4; bmt = (v >> 2) & 3; bnt = v & 3; }
  else         { bz = 0;      bmt = v >> 2;       bnt = v & 3; }
  const long m0 = (long)bmt * 256;
  const long n0 = (long)bnt * 256;
  A  += (long)bz * sA + m0 * lda;
  Bt += (long)bz * sB + n0 * ldb;

  const int r0   = tid >> 3;                       // rows 0..63 (L=0), +64 (L=1)
  const int cl   = ((tid & 7) ^ (r0 & 7)) * 8;     // (r&7) identical for r0,r0+64
  const int sdst = wave * 1024;                    // bytes; +8192 for L=1

  const short* Ard = As + wm * 8192 + l15 * 64;
  const short* Brd = Bs + (wn >> 1) * 8192 + ((wn & 1) * 64 + l15) * 64;
  const int sw0 = ((quad)     ^ (l15 & 7)) * 8;    // kh=0
  const int sw1 = ((4 + quad) ^ (l15 & 7)) * 8;    // kh=1

  f32x4 acc[8][4];
  const f32x4 z4 = {0.f, 0.f, 0.f, 0.f};
#pragma unroll
  for (int i = 0; i < 8; i++)
#pragma unroll
    for (int j = 0; j < 4; j++) acc[i][j] = z4;

  bf16x8 a0[4][2], a1[4][2], b0[2][2], b1[2][2];

  const int nT = K >> 6;  // even and >= 8 for all call sites

  STAGE_B(0, 0, 0)
  STAGE_B(0, 1, 0)
  STAGE_A(0, 0, 0)
  STAGE_A(0, 1, 0)
  STAGE_B(1, 0, 64)
  STAGE_B(1, 1, 64)
  STAGE_A(1, 0, 64)
  STAGE_A(1, 1, 64)
  asm volatile("s_waitcnt vmcnt(8)" ::: "memory");
  __builtin_amdgcn_s_barrier();
#pragma unroll
  for (int j = 0; j < 4; ++j) {
    a0[j][0] = *(const bf16x8*)(Ard + j * 1024 + sw0);
    a0[j][1] = *(const bf16x8*)(Ard + j * 1024 + sw1);
  }
#pragma unroll
  for (int j = 0; j < 2; ++j) {
    b0[j][0] = *(const bf16x8*)(Brd + j * 1024 + sw0);
    b0[j][1] = *(const bf16x8*)(Brd + j * 1024 + sw1);
  }

  for (int t = 0; t < nT; t += 2) {
    KTILE(t, 0)
    KTILE(t + 1, 1)
  }

  const long cbase = (long)bz * sC;
#pragma unroll
  for (int mt = 0; mt < 8; ++mt) {
#pragma unroll
    for (int nt = 0; nt < 4; ++nt) {
      const long col = n0 + wn * 64 + nt * 16 + l15;
      float bv = 0.f;
      if (MODE <= 1) bv = bias[col];
#pragma unroll
      for (int i = 0; i < 4; i++) {
        const long row = m0 + wm * 128 + mt * 16 + quad * 4 + i;
        float v2 = acc[mt][nt][i];
        if (MODE <= 1) v2 += bv;
        if (MODE == 0) v2 = fmaxf(v2, 0.f);
        o16[cbase + row * (long)N + col] = f2bf(v2);
      }
    }
  }
}

// standalone GEMM kernel (1D grid, nwg multiple of 8, chunked-XCD remap)
template <int MODE, bool BATCHED>
__global__ __launch_bounds__(512, 2) void gemm_bt(
    const short* __restrict__ A, const short* __restrict__ Bt,
    short* __restrict__ o16, const float* __restrict__ bias,
    int N, int K, long lda, long ldb, long sA, long sB, long sC)
{
  __shared__ __align__(16) short As[2 * 2 * 128 * 64];
  __shared__ __align__(16) short Bs[2 * 2 * 128 * 64];
  const int wgid = blockIdx.x;
  const int cpx  = gridDim.x >> 3;
  const int v    = (wgid & 7) * cpx + (wgid >> 3);
  gemm_core<MODE, BATCHED>(A, Bt, o16, bias, N, K, lda, ldb, sA, sB, sC, v, As, Bs);
}

// fused: blocks [0,ngemm) run the flat MODE-1 GEMM (qk projection);
// blocks [ngemm, ngemm + C*256) transpose tsrc (C batches of 1024x1024
// bf16) into tdst, one 64x64 tile per 512-thread block. Independent data.
__global__ __launch_bounds__(512, 2) void gemm_qk_tr(
    const short* __restrict__ A, const short* __restrict__ Bt,
    short* __restrict__ o16, const float* __restrict__ bias,
    int N, int K, long lda, long ldb,
    const short* __restrict__ tsrc, short* __restrict__ tdst, int ngemm)
{
  __shared__ __align__(16) short As[2 * 2 * 128 * 64];
  __shared__ __align__(16) short Bs[2 * 2 * 128 * 64];
  const int wgid = blockIdx.x;
  if (wgid < ngemm) {
    const int cpx = ngemm >> 3;
    const int v   = (wgid & 7) * cpx + (wgid >> 3);
    gemm_core<1, false>(A, Bt, o16, bias, N, K, lda, ldb, 0, 0, 0, v, As, Bs);
  } else {
    // 64x64 bf16 transpose tile, 512 threads: seg=tid&7 (16B col seg),
    // rr=tid>>3 (row 0..63). xor-swizzled LDS tile (8KB in As).
    short* tile = As;
    const int tb  = wgid - ngemm;
    const long base = (long)(tb >> 8) * 1048576L;
    const int rem = tb & 255;
    const int i0 = ((rem >> 4) & 15) * 64;
    const int d0 = (rem & 15) * 64;
    const int seg = threadIdx.x & 7;
    const int rr  = threadIdx.x >> 3;
    bf16x8 vv = *(const bf16x8*)(tsrc + base + (long)(i0 + rr) * 1024 + d0 + seg * 8);
#pragma unroll
    for (int j = 0; j < 8; ++j)
      tile[(seg * 8 + j) * 64 + (((rr >> 3) ^ seg) * 8) + (rr & 7)] = vv[j];
    __syncthreads();
    const int dd = rr;
    bf16x8 w = *(const bf16x8*)&tile[dd * 64 + ((seg ^ ((dd >> 3) & 7)) * 8)];
    *(bf16x8*)(tdst + base + (long)(d0 + dd) * 1024 + i0 + seg * 8) = w;
  }
}

// ---------------- f32 -> bf16 (grid: blocks*1024 == n)
__global__ __launch_bounds__(256) void cvt_bf16_k(const float* __restrict__ src,
                                                  short* __restrict__ dst) {
  long i = ((long)blockIdx.x * 256 + threadIdx.x) * 4;
  float4 v = *(const float4*)(src + i);
  short4 o;
  o.x = f2bf(v.x); o.y = f2bf(v.y); o.z = f2bf(v.z); o.w = f2bf(v.w);
  *(short4*)(dst + i) = o;
}

// ---------------- weight convert + transpose: dst[n][k] = bf16(src[k][n])
__global__ __launch_bounds__(256) void wcvt_t(const float* __restrict__ src,
                                              short* __restrict__ dst, int K, int N) {
  __shared__ float tile[32][33];
  int n0 = blockIdx.x * 32, k0 = blockIdx.y * 32;
  int tx = threadIdx.x & 31, ty = threadIdx.x >> 5;
#pragma unroll
  for (int j = 0; j < 4; j++) tile[ty + 8 * j][tx] = src[(long)(k0 + ty + 8 * j) * N + n0 + tx];
  __syncthreads();
#pragma unroll
  for (int j = 0; j < 4; j++) dst[(long)(n0 + ty + 8 * j) * K + k0 + tx] = f2bf(tile[tx][ty + 8 * j]);
}

// ---------------- bias concat
__global__ void concat_bias(const float* __restrict__ a, const float* __restrict__ b,
                            float* __restrict__ dst) {
  int t = threadIdx.x;
  dst[t] = a[t];
  dst[512 + t] = b[t];
}

// ---------------- rel_edges -> bitmask (bit set = keep)
__global__ __launch_bounds__(256) void mask_build(const float* __restrict__ rel,
                                                  unsigned long long* __restrict__ bits) {
  long row = blockIdx.x;
  const float* r = rel + row * 1024;
  unsigned long long* mrow = bits + row * 16;
  int t = threadIdx.x;
#pragma unroll
  for (int j = 0; j < 4; j++) {
    float v = r[t + 256 * j];
    unsigned long long m = __ballot(v != 0.f);
    if ((t & 63) == 0) mrow[(t >> 6) + 4 * j] = m;
  }
}

// ---------------- masked softmax in-place on bf16 scores (short4 vectorized)
// thread t handles elements 4t..4t+3; mask word mrow[t>>4], bit 4*(t&15)+j.
__global__ __launch_bounds__(256) void softmax_mask(short* __restrict__ sc,
                                                    const unsigned long long* __restrict__ bits) {
  __shared__ float red[8];
  long row = blockIdx.x;
  short* s = sc + row * 1024;
  const unsigned long long* mrow = bits + row * 16;
  int t = threadIdx.x, lane = t & 63, wave = t >> 6;
  short4 raw = *(const short4*)(s + 4 * t);
  unsigned long long w = mrow[t >> 4];
  int sh = (t & 15) * 4;
  short rv[4] = {raw.x, raw.y, raw.z, raw.w};
  float v[4];
  float mx = -3e38f;
#pragma unroll
  for (int j = 0; j < 4; j++) {
    bool keep = (w >> (sh + j)) & 1ULL;
    v[j] = keep ? bf2f(rv[j]) * SM_SCALE : -3e38f;
    mx = fmaxf(mx, v[j]);
  }
#pragma unroll
  for (int o = 32; o > 0; o >>= 1) mx = fmaxf(mx, __shfl_xor(mx, o, 64));
  if (lane == 0) red[wave] = mx;
  __syncthreads();
  mx = fmaxf(fmaxf(red[0], red[1]), fmaxf(red[2], red[3]));
  float e[4], sum = 0.f;
#pragma unroll
  for (int j = 0; j < 4; j++) {
    e[j] = (v[j] > -1e38f) ? __expf(v[j] - mx) : 0.f;
    sum += e[j];
  }
#pragma unroll
  for (int o = 32; o > 0; o >>= 1) sum += __shfl_xor(sum, o, 64);
  if (lane == 0) red[4 + wave] = sum;
  __syncthreads();
  sum = red[4] + red[5] + red[6] + red[7];
  float inv = 1.f / sum;
  short4 o4;
  o4.x = f2bf(e[0] * inv); o4.y = f2bf(e[1] * inv);
  o4.z = f2bf(e[2] * inv); o4.w = f2bf(e[3] * inv);
  *(short4*)(s + 4 * t) = o4;
}

// ---------------- residual + LayerNorm (short4/float4 vectorized).
// WOUT: write f32 out; WXB: update xb bf16.
template <bool WOUT, bool WXB>
__global__ __launch_bounds__(256) void ln_res(short* __restrict__ xb,
                                              const short* __restrict__ dlt,
                                              const float* __restrict__ g,
                                              const float* __restrict__ bb,
                                              float* __restrict__ o32) {
  __shared__ float red[8];
  long row = blockIdx.x;
  short* xr = xb + row * 1024;
  const short* dr = dlt + row * 1024;
  float* orow = o32 + row * 1024;
  int t = threadIdx.x, lane = t & 63, wave = t >> 6;
  short4 xv = *(const short4*)(xr + 4 * t);
  short4 dv = *(const short4*)(dr + 4 * t);
  short xa[4] = {xv.x, xv.y, xv.z, xv.w};
  short da[4] = {dv.x, dv.y, dv.z, dv.w};
  float y[4], s = 0.f;
#pragma unroll
  for (int j = 0; j < 4; j++) {
    y[j] = bf2f(xa[j]) + bf2f(da[j]);
    s += y[j];
  }
#pragma unroll
  for (int o = 32; o > 0; o >>= 1) s += __shfl_xor(s, o, 64);
  if (lane == 0) red[wave] = s;
  __syncthreads();
  s = red[0] + red[1] + red[2] + red[3];
  float mean = s * (1.f / 1024.f);
  float s2 = 0.f;
#pragma unroll
  for (int j = 0; j < 4; j++) { float d = y[j] - mean; s2 += d * d; }
#pragma unroll
  for (int o = 32; o > 0; o >>= 1) s2 += __shfl_xor(s2, o, 64);
  if (lane == 0) red[4 + wave] = s2;
  __syncthreads();
  s2 = red[4] + red[5] + red[6] + red[7];
  float rs = rsqrtf(s2 * (1.f / 1024.f) + 1e-5f);
  float4 gv = *(const float4*)(g + 4 * t);
  float4 bv = *(const float4*)(bb + 4 * t);
  float ga[4] = {gv.x, gv.y, gv.z, gv.w};
  float ba[4] = {bv.x, bv.y, bv.z, bv.w};
  float o[4];
#pragma unroll
  for (int j = 0; j < 4; j++) o[j] = (y[j] - mean) * rs * ga[j] + ba[j];
  if (WOUT) {
    float4 ov = {o[0], o[1], o[2], o[3]};
    *(float4*)(orow + 4 * t) = ov;
  }
  if (WXB) {
    short4 sv;
    sv.x = f2bf(o[0]); sv.y = f2bf(o[1]); sv.z = f2bf(o[2]); sv.w = f2bf(o[3]);
    *(short4*)(xr + 4 * t) = sv;
  }
}

extern "C" void kernel_launch(void* const* d_in, const int* in_sizes, int n_in,
                              void* d_out, int out_size, void* d_ws, size_t ws_size,
                              hipStream_t stream) {
  const float* node = (const float*)d_in[0];
  const float* rel  = (const float*)d_in[1];
  const float* Wemb = (const float*)d_in[2];
  const float* bemb = (const float*)d_in[3];
  const float* Wq   = (const float*)d_in[4];
  const float* bq   = (const float*)d_in[5];
  const float* Wk   = (const float*)d_in[6];
  const float* bk   = (const float*)d_in[7];
  const float* Wc   = (const float*)d_in[8];
  const float* lng  = (const float*)d_in[9];
  const float* lnb  = (const float*)d_in[10];
  float* out = (float*)d_out;

  // chunk C: need 81797120 + 8388608*C bytes
  int C = 0;
  for (int c = 32; c >= 1; c >>= 1)
    if (81797120ULL + 8388608ULL * (unsigned long long)c <= (unsigned long long)ws_size) { C = c; break; }
  if (C == 0) return;

  char* ws = (char*)d_ws;
  short* xb    = (short*)ws;                        // 32x1024x1024 bf16 (64 MB)
  short* WembT = (short*)(ws + 67108864);           // [1024][1024]
  short* WqkT  = (short*)(ws + 69206016);           // 2 x [1024][1024] (q|k)
  short* WcT   = (short*)(ws + 73400320);           // 2 x [1024][1024]
  float* bqk   = (float*)(ws + 77594624);           // 2 x [1024]
  unsigned long long* mbits = (unsigned long long*)(ws + 77602816);  // 4 MB
  char* chunk  = ws + 81797120;
  short* xbT  = (short*)chunk;                          // C x 1024x1024
  short* sc   = (short*)(chunk + (size_t)C * 2097152);  // C x 1024x1024
  short* ctx  = (short*)(chunk + (size_t)C * 4194304);  // C x 1024x1024
  short* qk   = (short*)(chunk + (size_t)C * 6291456);  // C x 1024x1024
  short* ctx2 = qk;                                     // alias

  // prep (tiny)
  wcvt_t<<<dim3(32, 32), 256, 0, stream>>>(Wemb, WembT, 1024, 1024);
  for (int l = 0; l < 2; ++l) {
    wcvt_t<<<dim3(16, 32), 256, 0, stream>>>(Wq + l * 524288, WqkT + l * 1048576,          1024, 512);
    wcvt_t<<<dim3(16, 32), 256, 0, stream>>>(Wk + l * 524288, WqkT + l * 1048576 + 524288, 1024, 512);
    wcvt_t<<<dim3(32, 32), 256, 0, stream>>>(Wc + l * 1048576, WcT + l * 1048576, 1024, 1024);
    concat_bias<<<1, 512, 0, stream>>>(bq + l * 512, bk + l * 512, bqk + l * 1024);
  }
  mask_build<<<32768, 256, 0, stream>>>(rel, mbits);

  const int NC = 32 / C;
  const int nwg = C * 16;

  // embedding: x = relu(node @ Wemb + bemb)
  for (int ch = 0; ch < NC; ++ch) {
    long b0 = (long)ch * C;
    cvt_bf16_k<<<C * 1024, 256, 0, stream>>>(node + b0 * 1048576, xbT);
    gemm_bt<0, false><<<nwg, 512, 0, stream>>>(
        xbT, WembT, xb + b0 * 1048576, bemb, 1024, 1024, 1024, 1024, 0, 0, 0);
  }

  for (int l = 0; l < 2; ++l) {
    for (int ch = 0; ch < NC; ++ch) {
      long b0 = (long)ch * C;
      short* xbc = xb + b0 * 1048576;
      // fused: qk projection GEMM + x transpose (independent)
      gemm_qk_tr<<<nwg + C * 256, 512, 0, stream>>>(
          xbc, WqkT + l * 1048576, qk, bqk + l * 1024, 1024, 1024, 1024, 1024,
          xbc, xbT, nwg);
      gemm_bt<2, true><<<nwg, 512, 0, stream>>>(
          qk, qk + 512, sc, nullptr, 1024, 512, 1024, 1024, 1048576, 1048576, 1048576);
      softmax_mask<<<C * 1024, 256, 0, stream>>>(sc, mbits + b0 * 16384);
      gemm_bt<2, true><<<nwg, 512, 0, stream>>>(
          sc, xbT, ctx, nullptr, 1024, 1024, 1024, 1024, 1048576, 1048576, 1048576);
      gemm_bt<2, false><<<nwg, 512, 0, stream>>>(
          ctx, WcT + l * 1048576, ctx2, nullptr, 1024, 1024, 1024, 1024, 0, 0, 0);
      if (l == 0)
        ln_res<false, true><<<C * 1024, 256, 0, stream>>>(xbc, ctx2, lng, lnb, nullptr);
      else
        ln_res<true, false><<<C * 1024, 256, 0, stream>>>(xbc, ctx2, lng + 1024, lnb + 1024,
                                                          out + b0 * 1048576);
    }
  }
}

// Round 12
// 1154.356 us; speedup vs baseline: 1.0120x; 1.0120x over previous
//
#include <hip/hip_runtime.h>

// GCNEncoder: B=32, N=1024, D=1024, L=2, D_FF=512
// R16 = R15 with setprio RESTORED. R15's A/B resolved: removing setprio
// cost ~8us/GEMM dispatch (total +47us) — m190's "setprio hurts lockstep
// GEMM" does not transfer to the R7 structure (phase-ahead preload gives
// wave role-diversity between barriers, so priority arbitration pays).
// Fusion kept: qk GEMM + x transpose in one launch (gemm_qk_tr measured
// 100.5us vs ~114us serial replacement).
// GEMM core (R7/R14): 256x256 tile, 8 waves, phase-ahead preload,
// 2 barriers/K-tile, vmcnt(4)@P3 / stage A@P4, chunked-XCD swizzle,
// xor-swizzled 128KiB LDS. nT even, M%256==0, N%256==0 at all sites.

#define SM_SCALE 0.04419417382415922f  // 1/sqrt(512)

using bf16x8 = __attribute__((ext_vector_type(8))) short;
using f32x4  = __attribute__((ext_vector_type(4))) float;

__device__ __forceinline__ short f2bf(float f) {
  union { float f; unsigned u; } x; x.f = f;
  unsigned r = x.u + 0x7fffu + ((x.u >> 16) & 1u);  // RNE
  return (short)(r >> 16);
}
__device__ __forceinline__ float bf2f(short s) {
  union { unsigned u; float f; } x;
  x.u = ((unsigned)(unsigned short)s) << 16;
  return x.f;
}

typedef const __attribute__((address_space(1))) void* gp1_t;
typedef __attribute__((address_space(3))) void* lp3_t;
__device__ __forceinline__ void ld_lds16(const void* g, void* l) {
  __builtin_amdgcn_global_load_lds((gp1_t)g, (lp3_t)l, 16, 0, 0);
}

// staging: one half-tile = [128][64] shorts; 512 threads x 2 loads x 16B.
// source col-group = (tid&7) ^ (row&7) so phys cg == logical cg ^ (row&7)
// (xor-swizzle, conflict-free ds_read_b128: 2 lanes/bank).
#define STAGE_A(BUF, AH, KO)                                                 \
  { const short* _sp = A + (long)((AH) * 128 + r0) * lda + (KO) + cl;        \
    char* _dp = (char*)As + (((BUF) * 32768) + ((AH) * 16384) + sdst);       \
    ld_lds16(_sp, _dp);                                                      \
    ld_lds16(_sp + 64 * lda, _dp + 8192); }

#define STAGE_B(BUF, BH, KO)                                                 \
  { const short* _sp = Bt + (long)((BH) * 128 + r0) * ldb + (KO) + cl;       \
    char* _dp = (char*)Bs + (((BUF) * 32768) + ((BH) * 16384) + sdst);       \
    ld_lds16(_sp, _dp);                                                      \
    ld_lds16(_sp + 64 * ldb, _dp + 8192); }

#define MFMA16(AF, BF, ACC_R, ACC_C)                                         \
  _Pragma("unroll") for (int j = 0; j < 4; ++j)                              \
    _Pragma("unroll") for (int n = 0; n < 2; ++n) {                          \
      acc[(ACC_R) + j][(ACC_C) + n] = __builtin_amdgcn_mfma_f32_16x16x32_bf16(\
          AF[j][0], BF[n][0], acc[(ACC_R) + j][(ACC_C) + n], 0, 0, 0);       \
      acc[(ACC_R) + j][(ACC_C) + n] = __builtin_amdgcn_mfma_f32_16x16x32_bf16(\
          AF[j][1], BF[n][1], acc[(ACC_R) + j][(ACC_C) + n], 0, 0, 0);       \
    }

#define KTILE(T, BUF)                                                        \
  {                                                                          \
    /* P1: preload b1(T); MFMA a0 x b0 -> acc[0..3][0..1] */                 \
    _Pragma("unroll") for (int j = 0; j < 2; ++j) {                          \
      b1[j][0] = *(const bf16x8*)(Brd + (BUF) * 16384 + (2 + j) * 1024 + sw0);\
      b1[j][1] = *(const bf16x8*)(Brd + (BUF) * 16384 + (2 + j) * 1024 + sw1);\
    }                                                                        \
    __builtin_amdgcn_s_setprio(1);                                           \
    MFMA16(a0, b0, 0, 0)                                                     \
    __builtin_amdgcn_s_setprio(0);                                           \
    /* P2: preload a1(T); MFMA a0 x b1 -> acc[0..3][2..3] */                 \
    _Pragma("unroll") for (int j = 0; j < 4; ++j) {                          \
      a1[j][0] = *(const bf16x8*)(Ard + (BUF) * 16384 + (4 + j) * 1024 + sw0);\
      a1[j][1] = *(const bf16x8*)(Ard + (BUF) * 16384 + (4 + j) * 1024 + sw1);\
    }                                                                        \
    __builtin_amdgcn_s_setprio(1);                                           \
    MFMA16(a0, b1, 0, 2)                                                     \
    __builtin_amdgcn_s_setprio(0);                                           \
    /* P3: publish reads; stage B(T+2)->buf(T); gate; preload a0(T+1) */     \
    asm volatile("s_waitcnt lgkmcnt(0)" ::: "memory");                       \
    __builtin_amdgcn_s_barrier();                                            \
    if ((T) + 2 < nT) {                                                      \
      STAGE_B((BUF), 0, ((T) + 2) * 64)                                      \
      STAGE_B((BUF), 1, ((T) + 2) * 64)                                      \
      asm volatile("s_waitcnt vmcnt(4)" ::: "memory");                       \
    } else {                                                                 \
      asm volatile("s_waitcnt vmcnt(0)" ::: "memory");                       \
    }                                                                        \
    __builtin_amdgcn_s_barrier();                                            \
    _Pragma("unroll") for (int j = 0; j < 4; ++j) {                          \
      a0[j][0] = *(const bf16x8*)(Ard + ((BUF) ^ 1) * 16384 + j * 1024 + sw0);\
      a0[j][1] = *(const bf16x8*)(Ard + ((BUF) ^ 1) * 16384 + j * 1024 + sw1);\
    }                                                                        \
    __builtin_amdgcn_s_setprio(1);                                           \
    MFMA16(a1, b0, 4, 0)                                                     \
    __builtin_amdgcn_s_setprio(0);                                           \
    /* P4: stage A(T+2)->buf(T); preload b0(T+1); MFMA a1 x b1 */            \
    if ((T) + 2 < nT) {                                                      \
      STAGE_A((BUF), 0, ((T) + 2) * 64)                                      \
      STAGE_A((BUF), 1, ((T) + 2) * 64)                                      \
    }                                                                        \
    _Pragma("unroll") for (int j = 0; j < 2; ++j) {                          \
      b0[j][0] = *(const bf16x8*)(Brd + ((BUF) ^ 1) * 16384 + j * 1024 + sw0);\
      b0[j][1] = *(const bf16x8*)(Brd + ((BUF) ^ 1) * 16384 + j * 1024 + sw1);\
    }                                                                        \
    __builtin_amdgcn_s_setprio(1);                                           \
    MFMA16(a1, b1, 4, 2)                                                     \
    __builtin_amdgcn_s_setprio(0);                                           \
  }

// ---------------- GEMM core: C(bf16) = A (MxK) * Bt^T (Bt NxK).
// v = virtual block id (already XCD-chunk swizzled). 512 threads.
template <int MODE, bool BATCHED>
__device__ __forceinline__ void gemm_core(
    const short* __restrict__ A, const short* __restrict__ Bt,
    short* __restrict__ o16, const float* __restrict__ bias,
    int N, int K, long lda, long ldb, long sA, long sB, long sC,
    int v, short* As, short* Bs)
{
  const int tid  = threadIdx.x;
  const int lane = tid & 63;
  const int wave = tid >> 6;        // 0..7
  const int wm = wave >> 2;         // 0..1 -> 128-row half
  const int wn = wave & 3;          // 0..3 -> 64-col slice
  const int l15 = lane & 15, quad = lane >> 4;
  int bz, bmt, bnt;
  if (BATCHED) { bz = v >> 4; bmt = (v >> 2) & 3; bnt = v & 3; }
  else         { bz = 0;      bmt = v >> 2;       bnt = v & 3; }
  const long m0 = (long)bmt * 256;
  const long n0 = (long)bnt * 256;
  A  += (long)bz * sA + m0 * lda;
  Bt += (long)bz * sB + n0 * ldb;

  const int r0   = tid >> 3;                       // rows 0..63 (L=0), +64 (L=1)
  const int cl   = ((tid & 7) ^ (r0 & 7)) * 8;     // (r&7) identical for r0,r0+64
  const int sdst = wave * 1024;                    // bytes; +8192 for L=1

  const short* Ard = As + wm * 8192 + l15 * 64;
  const short* Brd = Bs + (wn >> 1) * 8192 + ((wn & 1) * 64 + l15) * 64;
  const int sw0 = ((quad)     ^ (l15 & 7)) * 8;    // kh=0
  const int sw1 = ((4 + quad) ^ (l15 & 7)) * 8;    // kh=1

  f32x4 acc[8][4];
  const f32x4 z4 = {0.f, 0.f, 0.f, 0.f};
#pragma unroll
  for (int i = 0; i < 8; i++)
#pragma unroll
    for (int j = 0; j < 4; j++) acc[i][j] = z4;

  bf16x8 a0[4][2], a1[4][2], b0[2][2], b1[2][2];

  const int nT = K >> 6;  // even and >= 8 for all call sites

  STAGE_B(0, 0, 0)
  STAGE_B(0, 1, 0)
  STAGE_A(0, 0, 0)
  STAGE_A(0, 1, 0)
  STAGE_B(1, 0, 64)
  STAGE_B(1, 1, 64)
  STAGE_A(1, 0, 64)
  STAGE_A(1, 1, 64)
  asm volatile("s_waitcnt vmcnt(8)" ::: "memory");
  __builtin_amdgcn_s_barrier();
#pragma unroll
  for (int j = 0; j < 4; ++j) {
    a0[j][0] = *(const bf16x8*)(Ard + j * 1024 + sw0);
    a0[j][1] = *(const bf16x8*)(Ard + j * 1024 + sw1);
  }
#pragma unroll
  for (int j = 0; j < 2; ++j) {
    b0[j][0] = *(const bf16x8*)(Brd + j * 1024 + sw0);
    b0[j][1] = *(const bf16x8*)(Brd + j * 1024 + sw1);
  }

  for (int t = 0; t < nT; t += 2) {
    KTILE(t, 0)
    KTILE(t + 1, 1)
  }

  const long cbase = (long)bz * sC;
#pragma unroll
  for (int mt = 0; mt < 8; ++mt) {
#pragma unroll
    for (int nt = 0; nt < 4; ++nt) {
      const long col = n0 + wn * 64 + nt * 16 + l15;
      float bv = 0.f;
      if (MODE <= 1) bv = bias[col];
#pragma unroll
      for (int i = 0; i < 4; i++) {
        const long row = m0 + wm * 128 + mt * 16 + quad * 4 + i;
        float v2 = acc[mt][nt][i];
        if (MODE <= 1) v2 += bv;
        if (MODE == 0) v2 = fmaxf(v2, 0.f);
        o16[cbase + row * (long)N + col] = f2bf(v2);
      }
    }
  }
}

// standalone GEMM kernel (1D grid, nwg multiple of 8, chunked-XCD remap)
template <int MODE, bool BATCHED>
__global__ __launch_bounds__(512, 2) void gemm_bt(
    const short* __restrict__ A, const short* __restrict__ Bt,
    short* __restrict__ o16, const float* __restrict__ bias,
    int N, int K, long lda, long ldb, long sA, long sB, long sC)
{
  __shared__ __align__(16) short As[2 * 2 * 128 * 64];
  __shared__ __align__(16) short Bs[2 * 2 * 128 * 64];
  const int wgid = blockIdx.x;
  const int cpx  = gridDim.x >> 3;
  const int v    = (wgid & 7) * cpx + (wgid >> 3);
  gemm_core<MODE, BATCHED>(A, Bt, o16, bias, N, K, lda, ldb, sA, sB, sC, v, As, Bs);
}

// fused: blocks [0,ngemm) run the flat MODE-1 GEMM (qk projection);
// blocks [ngemm, ngemm + C*256) transpose tsrc (C batches of 1024x1024
// bf16) into tdst, one 64x64 tile per 512-thread block. Independent data.
__global__ __launch_bounds__(512, 2) void gemm_qk_tr(
    const short* __restrict__ A, const short* __restrict__ Bt,
    short* __restrict__ o16, const float* __restrict__ bias,
    int N, int K, long lda, long ldb,
    const short* __restrict__ tsrc, short* __restrict__ tdst, int ngemm)
{
  __shared__ __align__(16) short As[2 * 2 * 128 * 64];
  __shared__ __align__(16) short Bs[2 * 2 * 128 * 64];
  const int wgid = blockIdx.x;
  if (wgid < ngemm) {
    const int cpx = ngemm >> 3;
    const int v   = (wgid & 7) * cpx + (wgid >> 3);
    gemm_core<1, false>(A, Bt, o16, bias, N, K, lda, ldb, 0, 0, 0, v, As, Bs);
  } else {
    // 64x64 bf16 transpose tile, 512 threads: seg=tid&7 (16B col seg),
    // rr=tid>>3 (row 0..63). xor-swizzled LDS tile (8KB in As).
    short* tile = As;
    const int tb  = wgid - ngemm;
    const long base = (long)(tb >> 8) * 1048576L;
    const int rem = tb & 255;
    const int i0 = ((rem >> 4) & 15) * 64;
    const int d0 = (rem & 15) * 64;
    const int seg = threadIdx.x & 7;
    const int rr  = threadIdx.x >> 3;
    bf16x8 vv = *(const bf16x8*)(tsrc + base + (long)(i0 + rr) * 1024 + d0 + seg * 8);
#pragma unroll
    for (int j = 0; j < 8; ++j)
      tile[(seg * 8 + j) * 64 + (((rr >> 3) ^ seg) * 8) + (rr & 7)] = vv[j];
    __syncthreads();
    const int dd = rr;
    bf16x8 w = *(const bf16x8*)&tile[dd * 64 + ((seg ^ ((dd >> 3) & 7)) * 8)];
    *(bf16x8*)(tdst + base + (long)(d0 + dd) * 1024 + i0 + seg * 8) = w;
  }
}

// ---------------- f32 -> bf16 (grid: blocks*1024 == n)
__global__ __launch_bounds__(256) void cvt_bf16_k(const float* __restrict__ src,
                                                  short* __restrict__ dst) {
  long i = ((long)blockIdx.x * 256 + threadIdx.x) * 4;
  float4 v = *(const float4*)(src + i);
  short4 o;
  o.x = f2bf(v.x); o.y = f2bf(v.y); o.z = f2bf(v.z); o.w = f2bf(v.w);
  *(short4*)(dst + i) = o;
}

// ---------------- weight convert + transpose: dst[n][k] = bf16(src[k][n])
__global__ __launch_bounds__(256) void wcvt_t(const float* __restrict__ src,
                                              short* __restrict__ dst, int K, int N) {
  __shared__ float tile[32][33];
  int n0 = blockIdx.x * 32, k0 = blockIdx.y * 32;
  int tx = threadIdx.x & 31, ty = threadIdx.x >> 5;
#pragma unroll
  for (int j = 0; j < 4; j++) tile[ty + 8 * j][tx] = src[(long)(k0 + ty + 8 * j) * N + n0 + tx];
  __syncthreads();
#pragma unroll
  for (int j = 0; j < 4; j++) dst[(long)(n0 + ty + 8 * j) * K + k0 + tx] = f2bf(tile[tx][ty + 8 * j]);
}

// ---------------- bias concat
__global__ void concat_bias(const float* __restrict__ a, const float* __restrict__ b,
                            float* __restrict__ dst) {
  int t = threadIdx.x;
  dst[t] = a[t];
  dst[512 + t] = b[t];
}

// ---------------- rel_edges -> bitmask (bit set = keep)
__global__ __launch_bounds__(256) void mask_build(const float* __restrict__ rel,
                                                  unsigned long long* __restrict__ bits) {
  long row = blockIdx.x;
  const float* r = rel + row * 1024;
  unsigned long long* mrow = bits + row * 16;
  int t = threadIdx.x;
#pragma unroll
  for (int j = 0; j < 4; j++) {
    float v = r[t + 256 * j];
    unsigned long long m = __ballot(v != 0.f);
    if ((t & 63) == 0) mrow[(t >> 6) + 4 * j] = m;
  }
}

// ---------------- masked softmax in-place on bf16 scores (short4 vectorized)
// thread t handles elements 4t..4t+3; mask word mrow[t>>4], bit 4*(t&15)+j.
__global__ __launch_bounds__(256) void softmax_mask(short* __restrict__ sc,
                                                    const unsigned long long* __restrict__ bits) {
  __shared__ float red[8];
  long row = blockIdx.x;
  short* s = sc + row * 1024;
  const unsigned long long* mrow = bits + row * 16;
  int t = threadIdx.x, lane = t & 63, wave = t >> 6;
  short4 raw = *(const short4*)(s + 4 * t);
  unsigned long long w = mrow[t >> 4];
  int sh = (t & 15) * 4;
  short rv[4] = {raw.x, raw.y, raw.z, raw.w};
  float v[4];
  float mx = -3e38f;
#pragma unroll
  for (int j = 0; j < 4; j++) {
    bool keep = (w >> (sh + j)) & 1ULL;
    v[j] = keep ? bf2f(rv[j]) * SM_SCALE : -3e38f;
    mx = fmaxf(mx, v[j]);
  }
#pragma unroll
  for (int o = 32; o > 0; o >>= 1) mx = fmaxf(mx, __shfl_xor(mx, o, 64));
  if (lane == 0) red[wave] = mx;
  __syncthreads();
  mx = fmaxf(fmaxf(red[0], red[1]), fmaxf(red[2], red[3]));
  float e[4], sum = 0.f;
#pragma unroll
  for (int j = 0; j < 4; j++) {
    e[j] = (v[j] > -1e38f) ? __expf(v[j] - mx) : 0.f;
    sum += e[j];
  }
#pragma unroll
  for (int o = 32; o > 0; o >>= 1) sum += __shfl_xor(sum, o, 64);
  if (lane == 0) red[4 + wave] = sum;
  __syncthreads();
  sum = red[4] + red[5] + red[6] + red[7];
  float inv = 1.f / sum;
  short4 o4;
  o4.x = f2bf(e[0] * inv); o4.y = f2bf(e[1] * inv);
  o4.z = f2bf(e[2] * inv); o4.w = f2bf(e[3] * inv);
  *(short4*)(s + 4 * t) = o4;
}

// ---------------- residual + LayerNorm (short4/float4 vectorized).
// WOUT: write f32 out; WXB: update xb bf16.
template <bool WOUT, bool WXB>
__global__ __launch_bounds__(256) void ln_res(short* __restrict__ xb,
                                              const short* __restrict__ dlt,
                                              const float* __restrict__ g,
                                              const float* __restrict__ bb,
                                              float* __restrict__ o32) {
  __shared__ float red[8];
  long row = blockIdx.x;
  short* xr = xb + row * 1024;
  const short* dr = dlt + row * 1024;
  float* orow = o32 + row * 1024;
  int t = threadIdx.x, lane = t & 63, wave = t >> 6;
  short4 xv = *(const short4*)(xr + 4 * t);
  short4 dv = *(const short4*)(dr + 4 * t);
  short xa[4] = {xv.x, xv.y, xv.z, xv.w};
  short da[4] = {dv.x, dv.y, dv.z, dv.w};
  float y[4], s = 0.f;
#pragma unroll
  for (int j = 0; j < 4; j++) {
    y[j] = bf2f(xa[j]) + bf2f(da[j]);
    s += y[j];
  }
#pragma unroll
  for (int o = 32; o > 0; o >>= 1) s += __shfl_xor(s, o, 64);
  if (lane == 0) red[wave] = s;
  __syncthreads();
  s = red[0] + red[1] + red[2] + red[3];
  float mean = s * (1.f / 1024.f);
  float s2 = 0.f;
#pragma unroll
  for (int j = 0; j < 4; j++) { float d = y[j] - mean; s2 += d * d; }
#pragma unroll
  for (int o = 32; o > 0; o >>= 1) s2 += __shfl_xor(s2, o, 64);
  if (lane == 0) red[4 + wave] = s2;
  __syncthreads();
  s2 = red[4] + red[5] + red[6] + red[7];
  float rs = rsqrtf(s2 * (1.f / 1024.f) + 1e-5f);
  float4 gv = *(const float4*)(g + 4 * t);
  float4 bv = *(const float4*)(bb + 4 * t);
  float ga[4] = {gv.x, gv.y, gv.z, gv.w};
  float ba[4] = {bv.x, bv.y, bv.z, bv.w};
  float o[4];
#pragma unroll
  for (int j = 0; j < 4; j++) o[j] = (y[j] - mean) * rs * ga[j] + ba[j];
  if (WOUT) {
    float4 ov = {o[0], o[1], o[2], o[3]};
    *(float4*)(orow + 4 * t) = ov;
  }
  if (WXB) {
    short4 sv;
    sv.x = f2bf(o[0]); sv.y = f2bf(o[1]); sv.z = f2bf(o[2]); sv.w = f2bf(o[3]);
    *(short4*)(xr + 4 * t) = sv;
  }
}

extern "C" void kernel_launch(void* const* d_in, const int* in_sizes, int n_in,
                              void* d_out, int out_size, void* d_ws, size_t ws_size,
                              hipStream_t stream) {
  const float* node = (const float*)d_in[0];
  const float* rel  = (const float*)d_in[1];
  const float* Wemb = (const float*)d_in[2];
  const float* bemb = (const float*)d_in[3];
  const float* Wq   = (const float*)d_in[4];
  const float* bq   = (const float*)d_in[5];
  const float* Wk   = (const float*)d_in[6];
  const float* bk   = (const float*)d_in[7];
  const float* Wc   = (const float*)d_in[8];
  const float* lng  = (const float*)d_in[9];
  const float* lnb  = (const float*)d_in[10];
  float* out = (float*)d_out;

  // chunk C: need 81797120 + 8388608*C bytes
  int C = 0;
  for (int c = 32; c >= 1; c >>= 1)
    if (81797120ULL + 8388608ULL * (unsigned long long)c <= (unsigned long long)ws_size) { C = c; break; }
  if (C == 0) return;

  char* ws = (char*)d_ws;
  short* xb    = (short*)ws;                        // 32x1024x1024 bf16 (64 MB)
  short* WembT = (short*)(ws + 67108864);           // [1024][1024]
  short* WqkT  = (short*)(ws + 69206016);           // 2 x [1024][1024] (q|k)
  short* WcT   = (short*)(ws + 73400320);           // 2 x [1024][1024]
  float* bqk   = (float*)(ws + 77594624);           // 2 x [1024]
  unsigned long long* mbits = (unsigned long long*)(ws + 77602816);  // 4 MB
  char* chunk  = ws + 81797120;
  short* xbT  = (short*)chunk;                          // C x 1024x1024
  short* sc   = (short*)(chunk + (size_t)C * 2097152);  // C x 1024x1024
  short* ctx  = (short*)(chunk + (size_t)C * 4194304);  // C x 1024x1024
  short* qk   = (short*)(chunk + (size_t)C * 6291456);  // C x 1024x1024
  short* ctx2 = qk;                                     // alias

  // prep (tiny)
  wcvt_t<<<dim3(32, 32), 256, 0, stream>>>(Wemb, WembT, 1024, 1024);
  for (int l = 0; l < 2; ++l) {
    wcvt_t<<<dim3(16, 32), 256, 0, stream>>>(Wq + l * 524288, WqkT + l * 1048576,          1024, 512);
    wcvt_t<<<dim3(16, 32), 256, 0, stream>>>(Wk + l * 524288, WqkT + l * 1048576 + 524288, 1024, 512);
    wcvt_t<<<dim3(32, 32), 256, 0, stream>>>(Wc + l * 1048576, WcT + l * 1048576, 1024, 1024);
    concat_bias<<<1, 512, 0, stream>>>(bq + l * 512, bk + l * 512, bqk + l * 1024);
  }
  mask_build<<<32768, 256, 0, stream>>>(rel, mbits);

  const int NC = 32 / C;
  const int nwg = C * 16;

  // embedding: x = relu(node @ Wemb + bemb)
  for (int ch = 0; ch < NC; ++ch) {
    long b0 = (long)ch * C;
    cvt_bf16_k<<<C * 1024, 256, 0, stream>>>(node + b0 * 1048576, xbT);
    gemm_bt<0, false><<<nwg, 512, 0, stream>>>(
        xbT, WembT, xb + b0 * 1048576, bemb, 1024, 1024, 1024, 1024, 0, 0, 0);
  }

  for (int l = 0; l < 2; ++l) {
    for (int ch = 0; ch < NC; ++ch) {
      long b0 = (long)ch * C;
      short* xbc = xb + b0 * 1048576;
      // fused: qk projection GEMM + x transpose (independent)
      gemm_qk_tr<<<nwg + C * 256, 512, 0, stream>>>(
          xbc, WqkT + l * 1048576, qk, bqk + l * 1024, 1024, 1024, 1024, 1024,
          xbc, xbT, nwg);
      gemm_bt<2, true><<<nwg, 512, 0, stream>>>(
          qk, qk + 512, sc, nullptr, 1024, 512, 1024, 1024, 1048576, 1048576, 1048576);
      softmax_mask<<<C * 1024, 256, 0, stream>>>(sc, mbits + b0 * 16384);
      gemm_bt<2, true><<<nwg, 512, 0, stream>>>(
          sc, xbT, ctx, nullptr, 1024, 1024, 1024, 1024, 1048576, 1048576, 1048576);
      gemm_bt<2, false><<<nwg, 512, 0, stream>>>(
          ctx, WcT + l * 1048576, ctx2, nullptr, 1024, 1024, 1024, 1024, 0, 0, 0);
      if (l == 0)
        ln_res<false, true><<<C * 1024, 256, 0, stream>>>(xbc, ctx2, lng, lnb, nullptr);
      else
        ln_res<true, false><<<C * 1024, 256, 0, stream>>>(xbc, ctx2, lng + 1024, lnb + 1024,
                                                          out + b0 * 1048576);
    }
  }
}

// Round 13
// 1116.432 us; speedup vs baseline: 1.0463x; 1.0340x over previous
//
#include <hip/hip_runtime.h>

// GCNEncoder: B=32, N=1024, D=1024, L=2, D_FF=512
// R17 = revert to R14 (measured best, 1121us). R15/R16 A/B showed the
// qk+transpose fusion costs ~34us: LDS is per-KERNEL, so each of the
// 8192 fused transpose blocks reserved the GEMM's 128KiB static LDS
// while using 8KiB -> transpose ran at 1 block/CU instead of many,
// and couldn't co-reside with GEMM blocks (128+128 > 160KiB). Fusion
// with a fat-LDS kernel is structurally wrong. setprio kept (R15/R16
// A/B: +14us when removed).
// Components: R7 GEMM core (256x256 tile, 8 waves, phase-ahead preload,
// 2 barriers/K-tile, vmcnt(4)@P3 / stage A@P4, xor-swizzled 128KiB LDS)
// + chunked-XCD block swizzle (R14: FETCH -33%, gemm 94->88.5us)
// + vectorized softmax_mask / ln_res (R10) + standalone 8KiB transpose.
// nT even, M%256==0, N%256==0 at all call sites.

#define SM_SCALE 0.04419417382415922f  // 1/sqrt(512)

using bf16x8 = __attribute__((ext_vector_type(8))) short;
using f32x4  = __attribute__((ext_vector_type(4))) float;

__device__ __forceinline__ short f2bf(float f) {
  union { float f; unsigned u; } x; x.f = f;
  unsigned r = x.u + 0x7fffu + ((x.u >> 16) & 1u);  // RNE
  return (short)(r >> 16);
}
__device__ __forceinline__ float bf2f(short s) {
  union { unsigned u; float f; } x;
  x.u = ((unsigned)(unsigned short)s) << 16;
  return x.f;
}

typedef const __attribute__((address_space(1))) void* gp1_t;
typedef __attribute__((address_space(3))) void* lp3_t;
__device__ __forceinline__ void ld_lds16(const void* g, void* l) {
  __builtin_amdgcn_global_load_lds((gp1_t)g, (lp3_t)l, 16, 0, 0);
}

// staging: one half-tile = [128][64] shorts; 512 threads x 2 loads x 16B.
// source col-group = (tid&7) ^ (row&7) so phys cg == logical cg ^ (row&7)
// (xor-swizzle, conflict-free ds_read_b128: 2 lanes/bank).
#define STAGE_A(BUF, AH, KO)                                                 \
  { const short* _sp = A + (long)((AH) * 128 + r0) * lda + (KO) + cl;        \
    char* _dp = (char*)As + (((BUF) * 32768) + ((AH) * 16384) + sdst);       \
    ld_lds16(_sp, _dp);                                                      \
    ld_lds16(_sp + 64 * lda, _dp + 8192); }

#define STAGE_B(BUF, BH, KO)                                                 \
  { const short* _sp = Bt + (long)((BH) * 128 + r0) * ldb + (KO) + cl;       \
    char* _dp = (char*)Bs + (((BUF) * 32768) + ((BH) * 16384) + sdst);       \
    ld_lds16(_sp, _dp);                                                      \
    ld_lds16(_sp + 64 * ldb, _dp + 8192); }

#define MFMA16(AF, BF, ACC_R, ACC_C)                                         \
  _Pragma("unroll") for (int j = 0; j < 4; ++j)                              \
    _Pragma("unroll") for (int n = 0; n < 2; ++n) {                          \
      acc[(ACC_R) + j][(ACC_C) + n] = __builtin_amdgcn_mfma_f32_16x16x32_bf16(\
          AF[j][0], BF[n][0], acc[(ACC_R) + j][(ACC_C) + n], 0, 0, 0);       \
      acc[(ACC_R) + j][(ACC_C) + n] = __builtin_amdgcn_mfma_f32_16x16x32_bf16(\
          AF[j][1], BF[n][1], acc[(ACC_R) + j][(ACC_C) + n], 0, 0, 0);       \
    }

#define KTILE(T, BUF)                                                        \
  {                                                                          \
    /* P1: preload b1(T); MFMA a0 x b0 -> acc[0..3][0..1] */                 \
    _Pragma("unroll") for (int j = 0; j < 2; ++j) {                          \
      b1[j][0] = *(const bf16x8*)(Brd + (BUF) * 16384 + (2 + j) * 1024 + sw0);\
      b1[j][1] = *(const bf16x8*)(Brd + (BUF) * 16384 + (2 + j) * 1024 + sw1);\
    }                                                                        \
    __builtin_amdgcn_s_setprio(1);                                           \
    MFMA16(a0, b0, 0, 0)                                                     \
    __builtin_amdgcn_s_setprio(0);                                           \
    /* P2: preload a1(T); MFMA a0 x b1 -> acc[0..3][2..3] */                 \
    _Pragma("unroll") for (int j = 0; j < 4; ++j) {                          \
      a1[j][0] = *(const bf16x8*)(Ard + (BUF) * 16384 + (4 + j) * 1024 + sw0);\
      a1[j][1] = *(const bf16x8*)(Ard + (BUF) * 16384 + (4 + j) * 1024 + sw1);\
    }                                                                        \
    __builtin_amdgcn_s_setprio(1);                                           \
    MFMA16(a0, b1, 0, 2)                                                     \
    __builtin_amdgcn_s_setprio(0);                                           \
    /* P3: publish reads; stage B(T+2)->buf(T); gate; preload a0(T+1) */     \
    asm volatile("s_waitcnt lgkmcnt(0)" ::: "memory");                       \
    __builtin_amdgcn_s_barrier();                                            \
    if ((T) + 2 < nT) {                                                      \
      STAGE_B((BUF), 0, ((T) + 2) * 64)                                      \
      STAGE_B((BUF), 1, ((T) + 2) * 64)                                      \
      asm volatile("s_waitcnt vmcnt(4)" ::: "memory");                       \
    } else {                                                                 \
      asm volatile("s_waitcnt vmcnt(0)" ::: "memory");                       \
    }                                                                        \
    __builtin_amdgcn_s_barrier();                                            \
    _Pragma("unroll") for (int j = 0; j < 4; ++j) {                          \
      a0[j][0] = *(const bf16x8*)(Ard + ((BUF) ^ 1) * 16384 + j * 1024 + sw0);\
      a0[j][1] = *(const bf16x8*)(Ard + ((BUF) ^ 1) * 16384 + j * 1024 + sw1);\
    }                                                                        \
    __builtin_amdgcn_s_setprio(1);                                           \
    MFMA16(a1, b0, 4, 0)                                                     \
    __builtin_amdgcn_s_setprio(0);                                           \
    /* P4: stage A(T+2)->buf(T); preload b0(T+1); MFMA a1 x b1 */            \
    if ((T) + 2 < nT) {                                                      \
      STAGE_A((BUF), 0, ((T) + 2) * 64)                                      \
      STAGE_A((BUF), 1, ((T) + 2) * 64)                                      \
    }                                                                        \
    _Pragma("unroll") for (int j = 0; j < 2; ++j) {                          \
      b0[j][0] = *(const bf16x8*)(Brd + ((BUF) ^ 1) * 16384 + j * 1024 + sw0);\
      b0[j][1] = *(const bf16x8*)(Brd + ((BUF) ^ 1) * 16384 + j * 1024 + sw1);\
    }                                                                        \
    __builtin_amdgcn_s_setprio(1);                                           \
    MFMA16(a1, b1, 4, 2)                                                     \
    __builtin_amdgcn_s_setprio(0);                                           \
  }

// ---------------- C(bf16) = A (MxK, row stride lda) * Bt^T (Bt NxK, stride ldb)
// MODE 0: relu(acc+bias)  MODE 1: acc+bias  MODE 2: acc
// 1D grid, nwg = C*16 (multiple of 8). Chunked-XCD remap inside.
template <int MODE, bool BATCHED>
__global__ __launch_bounds__(512, 2) void gemm_bt(
    const short* __restrict__ A, const short* __restrict__ Bt,
    short* __restrict__ o16, const float* __restrict__ bias,
    int N, int K, long lda, long ldb, long sA, long sB, long sC)
{
  __shared__ __align__(16) short As[2 * 2 * 128 * 64];  // [buf][half][128][64]
  __shared__ __align__(16) short Bs[2 * 2 * 128 * 64];
  const int tid  = threadIdx.x;
  const int lane = tid & 63;
  const int wave = tid >> 6;        // 0..7
  const int wm = wave >> 2;         // 0..1 -> 128-row half
  const int wn = wave & 3;          // 0..3 -> 64-col slice
  const int l15 = lane & 15, quad = lane >> 4;

  // chunked-XCD swizzle: consecutive wgid round-robin across XCDs ->
  // each XCD gets a contiguous range of virtual ids v.
  const int wgid = blockIdx.x;
  const int cpx  = gridDim.x >> 3;                 // nwg/8, exact
  const int v    = (wgid & 7) * cpx + (wgid >> 3);
  int bz, bmt, bnt;
  if (BATCHED) { bz = v >> 4; bmt = (v >> 2) & 3; bnt = v & 3; }
  else         { bz = 0;      bmt = v >> 2;       bnt = v & 3; }
  const long m0 = (long)bmt * 256;
  const long n0 = (long)bnt * 256;
  A  += (long)bz * sA + m0 * lda;
  Bt += (long)bz * sB + n0 * ldb;

  // staging address components (see STAGE_* macros)
  const int r0   = tid >> 3;                       // rows 0..63 (L=0), +64 (L=1)
  const int cl   = ((tid & 7) ^ (r0 & 7)) * 8;     // (r&7) identical for r0,r0+64
  const int sdst = wave * 1024;                    // bytes; +8192 for L=1

  // fragment-read bases (short units) + swizzled k-group offsets
  const short* Ard = As + wm * 8192 + l15 * 64;
  const short* Brd = Bs + (wn >> 1) * 8192 + ((wn & 1) * 64 + l15) * 64;
  const int sw0 = ((quad)     ^ (l15 & 7)) * 8;    // kh=0
  const int sw1 = ((4 + quad) ^ (l15 & 7)) * 8;    // kh=1

  f32x4 acc[8][4];
  const f32x4 z4 = {0.f, 0.f, 0.f, 0.f};
#pragma unroll
  for (int i = 0; i < 8; i++)
#pragma unroll
    for (int j = 0; j < 4; j++) acc[i][j] = z4;

  bf16x8 a0[4][2], a1[4][2], b0[2][2], b1[2][2];

  const int nT = K >> 6;  // even and >= 8 for all call sites

  // prologue: stage tiles 0 and 1 (16 vmcnt instr); vmcnt(8) = tile0
  // landed, tile1's 8 in flight; pre-read a0,b0 of tile 0.
  STAGE_B(0, 0, 0)
  STAGE_B(0, 1, 0)
  STAGE_A(0, 0, 0)
  STAGE_A(0, 1, 0)
  STAGE_B(1, 0, 64)
  STAGE_B(1, 1, 64)
  STAGE_A(1, 0, 64)
  STAGE_A(1, 1, 64)
  asm volatile("s_waitcnt vmcnt(8)" ::: "memory");
  __builtin_amdgcn_s_barrier();
#pragma unroll
  for (int j = 0; j < 4; ++j) {
    a0[j][0] = *(const bf16x8*)(Ard + j * 1024 + sw0);
    a0[j][1] = *(const bf16x8*)(Ard + j * 1024 + sw1);
  }
#pragma unroll
  for (int j = 0; j < 2; ++j) {
    b0[j][0] = *(const bf16x8*)(Brd + j * 1024 + sw0);
    b0[j][1] = *(const bf16x8*)(Brd + j * 1024 + sw1);
  }

  for (int t = 0; t < nT; t += 2) {
    KTILE(t, 0)
    KTILE(t + 1, 1)
  }

  const long cbase = (long)bz * sC;
#pragma unroll
  for (int mt = 0; mt < 8; ++mt) {
#pragma unroll
    for (int nt = 0; nt < 4; ++nt) {
      const long col = n0 + wn * 64 + nt * 16 + l15;
      float bv = 0.f;
      if (MODE <= 1) bv = bias[col];
#pragma unroll
      for (int i = 0; i < 4; i++) {
        const long row = m0 + wm * 128 + mt * 16 + quad * 4 + i;
        float v2 = acc[mt][nt][i];
        if (MODE <= 1) v2 += bv;
        if (MODE == 0) v2 = fmaxf(v2, 0.f);
        o16[cbase + row * (long)N + col] = f2bf(v2);
      }
    }
  }
}

// ---------------- f32 -> bf16 (grid: blocks*1024 == n)
__global__ __launch_bounds__(256) void cvt_bf16_k(const float* __restrict__ src,
                                                  short* __restrict__ dst) {
  long i = ((long)blockIdx.x * 256 + threadIdx.x) * 4;
  float4 v = *(const float4*)(src + i);
  short4 o;
  o.x = f2bf(v.x); o.y = f2bf(v.y); o.z = f2bf(v.z); o.w = f2bf(v.w);
  *(short4*)(dst + i) = o;
}

// ---------------- weight convert + transpose: dst[n][k] = bf16(src[k][n])
__global__ __launch_bounds__(256) void wcvt_t(const float* __restrict__ src,
                                              short* __restrict__ dst, int K, int N) {
  __shared__ float tile[32][33];
  int n0 = blockIdx.x * 32, k0 = blockIdx.y * 32;
  int tx = threadIdx.x & 31, ty = threadIdx.x >> 5;
#pragma unroll
  for (int j = 0; j < 4; j++) tile[ty + 8 * j][tx] = src[(long)(k0 + ty + 8 * j) * N + n0 + tx];
  __syncthreads();
#pragma unroll
  for (int j = 0; j < 4; j++) dst[(long)(n0 + ty + 8 * j) * K + k0 + tx] = f2bf(tile[tx][ty + 8 * j]);
}

// ---------------- bias concat
__global__ void concat_bias(const float* __restrict__ a, const float* __restrict__ b,
                            float* __restrict__ dst) {
  int t = threadIdx.x;
  dst[t] = a[t];
  dst[512 + t] = b[t];
}

// ---------------- rel_edges -> bitmask (bit set = keep)
__global__ __launch_bounds__(256) void mask_build(const float* __restrict__ rel,
                                                  unsigned long long* __restrict__ bits) {
  long row = blockIdx.x;
  const float* r = rel + row * 1024;
  unsigned long long* mrow = bits + row * 16;
  int t = threadIdx.x;
#pragma unroll
  for (int j = 0; j < 4; j++) {
    float v = r[t + 256 * j];
    unsigned long long m = __ballot(v != 0.f);
    if ((t & 63) == 0) mrow[(t >> 6) + 4 * j] = m;
  }
}

// ---------------- per-batch bf16 transpose, 64x64 tiles, 16B IO, xor-swizzled LDS
__global__ __launch_bounds__(256) void transpose_bf16(const short* __restrict__ src,
                                                      short* __restrict__ dst) {
  __shared__ short tile[64 * 64];
  long base = (long)blockIdx.z * 1048576L;
  int i0 = blockIdx.y * 64, d0 = blockIdx.x * 64;
  int seg = threadIdx.x & 7;
  int r   = threadIdx.x >> 3;
#pragma unroll
  for (int p = 0; p < 2; ++p) {
    int rr = r + 32 * p;
    bf16x8 v = *(const bf16x8*)(src + base + (long)(i0 + rr) * 1024 + d0 + seg * 8);
#pragma unroll
    for (int j = 0; j < 8; ++j)
      tile[(seg * 8 + j) * 64 + (((rr >> 3) ^ seg) * 8) + (rr & 7)] = v[j];
  }
  __syncthreads();
#pragma unroll
  for (int p = 0; p < 2; ++p) {
    int dd = r + 32 * p;
    bf16x8 v = *(const bf16x8*)&tile[dd * 64 + ((seg ^ ((dd >> 3) & 7)) * 8)];
    *(bf16x8*)(dst + base + (long)(d0 + dd) * 1024 + i0 + seg * 8) = v;
  }
}

// ---------------- masked softmax in-place on bf16 scores (short4 vectorized)
// thread t handles elements 4t..4t+3; mask word mrow[t>>4], bit 4*(t&15)+j.
__global__ __launch_bounds__(256) void softmax_mask(short* __restrict__ sc,
                                                    const unsigned long long* __restrict__ bits) {
  __shared__ float red[8];
  long row = blockIdx.x;
  short* s = sc + row * 1024;
  const unsigned long long* mrow = bits + row * 16;
  int t = threadIdx.x, lane = t & 63, wave = t >> 6;
  short4 raw = *(const short4*)(s + 4 * t);
  unsigned long long w = mrow[t >> 4];
  int sh = (t & 15) * 4;
  short rv[4] = {raw.x, raw.y, raw.z, raw.w};
  float v[4];
  float mx = -3e38f;
#pragma unroll
  for (int j = 0; j < 4; j++) {
    bool keep = (w >> (sh + j)) & 1ULL;
    v[j] = keep ? bf2f(rv[j]) * SM_SCALE : -3e38f;
    mx = fmaxf(mx, v[j]);
  }
#pragma unroll
  for (int o = 32; o > 0; o >>= 1) mx = fmaxf(mx, __shfl_xor(mx, o, 64));
  if (lane == 0) red[wave] = mx;
  __syncthreads();
  mx = fmaxf(fmaxf(red[0], red[1]), fmaxf(red[2], red[3]));
  float e[4], sum = 0.f;
#pragma unroll
  for (int j = 0; j < 4; j++) {
    e[j] = (v[j] > -1e38f) ? __expf(v[j] - mx) : 0.f;
    sum += e[j];
  }
#pragma unroll
  for (int o = 32; o > 0; o >>= 1) sum += __shfl_xor(sum, o, 64);
  if (lane == 0) red[4 + wave] = sum;
  __syncthreads();
  sum = red[4] + red[5] + red[6] + red[7];
  float inv = 1.f / sum;
  short4 o4;
  o4.x = f2bf(e[0] * inv); o4.y = f2bf(e[1] * inv);
  o4.z = f2bf(e[2] * inv); o4.w = f2bf(e[3] * inv);
  *(short4*)(s + 4 * t) = o4;
}

// ---------------- residual + LayerNorm (short4/float4 vectorized).
// WOUT: write f32 out; WXB: update xb bf16.
template <bool WOUT, bool WXB>
__global__ __launch_bounds__(256) void ln_res(short* __restrict__ xb,
                                              const short* __restrict__ dlt,
                                              const float* __restrict__ g,
                                              const float* __restrict__ bb,
                                              float* __restrict__ o32) {
  __shared__ float red[8];
  long row = blockIdx.x;
  short* xr = xb + row * 1024;
  const short* dr = dlt + row * 1024;
  float* orow = o32 + row * 1024;
  int t = threadIdx.x, lane = t & 63, wave = t >> 6;
  short4 xv = *(const short4*)(xr + 4 * t);
  short4 dv = *(const short4*)(dr + 4 * t);
  short xa[4] = {xv.x, xv.y, xv.z, xv.w};
  short da[4] = {dv.x, dv.y, dv.z, dv.w};
  float y[4], s = 0.f;
#pragma unroll
  for (int j = 0; j < 4; j++) {
    y[j] = bf2f(xa[j]) + bf2f(da[j]);
    s += y[j];
  }
#pragma unroll
  for (int o = 32; o > 0; o >>= 1) s += __shfl_xor(s, o, 64);
  if (lane == 0) red[wave] = s;
  __syncthreads();
  s = red[0] + red[1] + red[2] + red[3];
  float mean = s * (1.f / 1024.f);
  float s2 = 0.f;
#pragma unroll
  for (int j = 0; j < 4; j++) { float d = y[j] - mean; s2 += d * d; }
#pragma unroll
  for (int o = 32; o > 0; o >>= 1) s2 += __shfl_xor(s2, o, 64);
  if (lane == 0) red[4 + wave] = s2;
  __syncthreads();
  s2 = red[4] + red[5] + red[6] + red[7];
  float rs = rsqrtf(s2 * (1.f / 1024.f) + 1e-5f);
  float4 gv = *(const float4*)(g + 4 * t);
  float4 bv = *(const float4*)(bb + 4 * t);
  float ga[4] = {gv.x, gv.y, gv.z, gv.w};
  float ba[4] = {bv.x, bv.y, bv.z, bv.w};
  float o[4];
#pragma unroll
  for (int j = 0; j < 4; j++) o[j] = (y[j] - mean) * rs * ga[j] + ba[j];
  if (WOUT) {
    float4 ov = {o[0], o[1], o[2], o[3]};
    *(float4*)(orow + 4 * t) = ov;
  }
  if (WXB) {
    short4 sv;
    sv.x = f2bf(o[0]); sv.y = f2bf(o[1]); sv.z = f2bf(o[2]); sv.w = f2bf(o[3]);
    *(short4*)(xr + 4 * t) = sv;
  }
}

extern "C" void kernel_launch(void* const* d_in, const int* in_sizes, int n_in,
                              void* d_out, int out_size, void* d_ws, size_t ws_size,
                              hipStream_t stream) {
  const float* node = (const float*)d_in[0];
  const float* rel  = (const float*)d_in[1];
  const float* Wemb = (const float*)d_in[2];
  const float* bemb = (const float*)d_in[3];
  const float* Wq   = (const float*)d_in[4];
  const float* bq   = (const float*)d_in[5];
  const float* Wk   = (const float*)d_in[6];
  const float* bk   = (const float*)d_in[7];
  const float* Wc   = (const float*)d_in[8];
  const float* lng  = (const float*)d_in[9];
  const float* lnb  = (const float*)d_in[10];
  float* out = (float*)d_out;

  // chunk C: need 81797120 + 8388608*C bytes
  int C = 0;
  for (int c = 32; c >= 1; c >>= 1)
    if (81797120ULL + 8388608ULL * (unsigned long long)c <= (unsigned long long)ws_size) { C = c; break; }
  if (C == 0) return;

  char* ws = (char*)d_ws;
  short* xb    = (short*)ws;                        // 32x1024x1024 bf16 (64 MB)
  short* WembT = (short*)(ws + 67108864);           // [1024][1024]
  short* WqkT  = (short*)(ws + 69206016);           // 2 x [1024][1024] (q|k)
  short* WcT   = (short*)(ws + 73400320);           // 2 x [1024][1024]
  float* bqk   = (float*)(ws + 77594624);           // 2 x [1024]
  unsigned long long* mbits = (unsigned long long*)(ws + 77602816);  // 4 MB
  char* chunk  = ws + 81797120;
  short* xbT  = (short*)chunk;                          // C x 1024x1024
  short* sc   = (short*)(chunk + (size_t)C * 2097152);  // C x 1024x1024
  short* ctx  = (short*)(chunk + (size_t)C * 4194304);  // C x 1024x1024
  short* qk   = (short*)(chunk + (size_t)C * 6291456);  // C x 1024x1024
  short* ctx2 = qk;                                     // alias

  // prep (tiny)
  wcvt_t<<<dim3(32, 32), 256, 0, stream>>>(Wemb, WembT, 1024, 1024);
  for (int l = 0; l < 2; ++l) {
    wcvt_t<<<dim3(16, 32), 256, 0, stream>>>(Wq + l * 524288, WqkT + l * 1048576,          1024, 512);
    wcvt_t<<<dim3(16, 32), 256, 0, stream>>>(Wk + l * 524288, WqkT + l * 1048576 + 524288, 1024, 512);
    wcvt_t<<<dim3(32, 32), 256, 0, stream>>>(Wc + l * 1048576, WcT + l * 1048576, 1024, 1024);
    concat_bias<<<1, 512, 0, stream>>>(bq + l * 512, bk + l * 512, bqk + l * 1024);
  }
  mask_build<<<32768, 256, 0, stream>>>(rel, mbits);

  const int NC = 32 / C;
  const int nwg = C * 16;

  // embedding: x = relu(node @ Wemb + bemb)
  for (int ch = 0; ch < NC; ++ch) {
    long b0 = (long)ch * C;
    cvt_bf16_k<<<C * 1024, 256, 0, stream>>>(node + b0 * 1048576, xbT);
    gemm_bt<0, false><<<nwg, 512, 0, stream>>>(
        xbT, WembT, xb + b0 * 1048576, bemb, 1024, 1024, 1024, 1024, 0, 0, 0);
  }

  for (int l = 0; l < 2; ++l) {
    for (int ch = 0; ch < NC; ++ch) {
      long b0 = (long)ch * C;
      short* xbc = xb + b0 * 1048576;
      transpose_bf16<<<dim3(16, 16, C), 256, 0, stream>>>(xbc, xbT);
      gemm_bt<1, false><<<nwg, 512, 0, stream>>>(
          xbc, WqkT + l * 1048576, qk, bqk + l * 1024, 1024, 1024, 1024, 1024, 0, 0, 0);
      gemm_bt<2, true><<<nwg, 512, 0, stream>>>(
          qk, qk + 512, sc, nullptr, 1024, 512, 1024, 1024, 1048576, 1048576, 1048576);
      softmax_mask<<<C * 1024, 256, 0, stream>>>(sc, mbits + b0 * 16384);
      gemm_bt<2, true><<<nwg, 512, 0, stream>>>(
          sc, xbT, ctx, nullptr, 1024, 1024, 1024, 1024, 1048576, 1048576, 1048576);
      gemm_bt<2, false><<<nwg, 512, 0, stream>>>(
          ctx, WcT + l * 1048576, ctx2, nullptr, 1024, 1024, 1024, 1024, 0, 0, 0);
      if (l == 0)
        ln_res<false, true><<<C * 1024, 256, 0, stream>>>(xbc, ctx2, lng, lnb, nullptr);
      else
        ln_res<true, false><<<C * 1024, 256, 0, stream>>>(xbc, ctx2, lng + 1024, lnb + 1024,
                                                          out + b0 * 1048576);
    }
  }
}